// Round 4
// baseline (20437.164 us; speedup 1.0000x reference)
//
#include <hip/hip_runtime.h>
#include <cstdint>
#include <cstddef>

// Problem constants
#define BB 32
#define TT 1024
#define DD 512
#define HH 512
#define NBLK 64            // each block runs BOTH cells (fwd + bwd), 8 cols each
#define NTHR 512           // 8 waves: wid>>2 = dir, (wid>>1)&1 = mi, wid&1 = ni

typedef __bf16 bf16x8 __attribute__((ext_vector_type(8)));
typedef float  f32x4  __attribute__((ext_vector_type(4)));
typedef unsigned long long u64;

// Sentinel: bf16 NaN. h = o*tanh(c) in (-1,1) can never be NaN, so a
// written (h_lo,h_hi) u32 can never equal CLR32. f32 NaN for the x ring.
#define CLR32  0x7FC07FC0u
#define CLRF   0x7FC00000u

// ws layout (bytes):
//   hfrag : ushort[4 buf][2 dir][2 ni][16 s][64 lane][8] = 131072 us = 262144 B @ 0
//   xhat  : float [2 pass][TT][BB] (epilogue output)      = 262144 B @ 262144
//   xring : float [4 buf][BB] (NaN-cleared feedback ring) =    512 B @ 524288
//   iflags: int   [NBLK] (init barrier only)              =    256 B @ 524800
#define HFRAG_OFF 0
#define XHAT_OFF  262144
#define XRING_OFF 524288
#define IFLAG_OFF 524800

#define AT_LOAD(p)     __hip_atomic_load((p),      __ATOMIC_RELAXED, __HIP_MEMORY_SCOPE_AGENT)
#define AT_STORE(p, v) __hip_atomic_store((p), (v), __ATOMIC_RELAXED, __HIP_MEMORY_SCOPE_AGENT)

__device__ __forceinline__ float sigm(float x) {
    return 1.f / (1.f + __expf(-x));
}
__device__ __forceinline__ float tanh_fast(float x) {
    x = fminf(15.f, fmaxf(-15.f, x));
    float e = __expf(2.f * x);
    return (e - 1.f) / (e + 1.f);
}

// ---- init barrier (only barrier in the kernel) --------------------------
// Ensures every block's buffer zero/sentinel init completed at the LLC
// before anyone starts polling data.
__device__ __forceinline__ void arrive_flag(int* iflags, int bid) {
    __builtin_amdgcn_s_waitcnt(0);
    __syncthreads();
    if (threadIdx.x == 0) AT_STORE(&iflags[bid], 1);
}
__device__ __forceinline__ void wait_flag(const int* iflags) {
    if (threadIdx.x < 64) {
        for (;;) {
            int v = AT_LOAD(&iflags[threadIdx.x]);
            if (__all(v >= 1)) break;
            __builtin_amdgcn_s_sleep(1);
        }
    }
    __syncthreads();
}

// input-side GEMM half: 8 K-tiles of u_t @ wih^T accumulated into un0/un1.
#define UGEMM_HALF(tt, S0)                                                    \
  {                                                                           \
    const float* ub = u + (size_t)bc * (TT * DD) + (size_t)(tt) * DD + quad * 8; \
    _Pragma("unroll")                                                         \
    for (int i8 = 0; i8 < 8; ++i8) {                                          \
      const int s = (S0) + i8;                                                \
      const float4* p = (const float4*)(ub + s * 32);                         \
      float4 x0 = p[0], x1 = p[1];                                            \
      bf16x8 uf;                                                              \
      uf[0] = (__bf16)x0.x; uf[1] = (__bf16)x0.y;                             \
      uf[2] = (__bf16)x0.z; uf[3] = (__bf16)x0.w;                             \
      uf[4] = (__bf16)x1.x; uf[5] = (__bf16)x1.y;                             \
      uf[6] = (__bf16)x1.z; uf[7] = (__bf16)x1.w;                             \
      if (s & 1) un1 = __builtin_amdgcn_mfma_f32_16x16x32_bf16(wihF[s], uf, un1, 0, 0, 0); \
      else       un0 = __builtin_amdgcn_mfma_f32_16x16x32_bf16(wihF[s], uf, un0, 0, 0, 0); \
    }                                                                         \
  }

__global__ __launch_bounds__(NTHR, 1) void lstm_persistent(
    const float* __restrict__ u,
    const float* __restrict__ wih_f, const float* __restrict__ whh_f,
    const float* __restrict__ bih_f, const float* __restrict__ bhh_f,
    const float* __restrict__ wih_b, const float* __restrict__ whh_b,
    const float* __restrict__ bih_b, const float* __restrict__ bhh_b,
    unsigned short* __restrict__ hfrag, float* __restrict__ xhat,
    unsigned* __restrict__ xring, int* __restrict__ iflags)
{
    const int bid  = blockIdx.x;      // 0..63 : hidden-column block (both dirs)
    const int k0   = bid << 3;        // 8 hidden columns per block
    const int tid  = threadIdx.x;
    const int wid  = tid >> 6;        // 8 waves
    const int dir  = wid >> 2;        // waves 0-3: forward cell, 4-7: backward
    const int mi   = (wid >> 1) & 1;  // col-group half (4 cols each)
    const int ni   = wid & 1;         // batch half (16 batches each)
    const int lane = tid & 63;
    const int quad = lane >> 4;
    const int l16  = lane & 15;

    const float* wih = dir ? wih_b : wih_f;
    const float* whh = dir ? whh_b : whh_f;
    const float* bih = dir ? bih_b : bih_f;
    const float* bhh = dir ? bhh_b : bhh_f;

    // ---- A-fragments (weights) pinned in registers for the whole kernel ----
    bf16x8 wihF[16], whhF[16];
    {
        const int jg = (l16 >> 2) * HH + (k0 + 4 * mi) + (l16 & 3);
        #pragma unroll
        for (int s = 0; s < 16; ++s) {
            const float* p = wih + (size_t)jg * DD + s * 32 + quad * 8;
            const float* q = whh + (size_t)jg * HH + s * 32 + quad * 8;
            bf16x8 a, b;
            #pragma unroll
            for (int i = 0; i < 8; ++i) { a[i] = (__bf16)p[i]; b[i] = (__bf16)q[i]; }
            wihF[s] = a;
            whhF[s] = b;
        }
    }

    // ---- per-lane cell: (kc = k0 + 4*mi + quad, bc = ni*16 + l16) ----
    const int kc = k0 + 4 * mi + quad;
    const int bc = ni * 16 + l16;

    // rowsum(W_ih) from the frags (bf16-rounded terms == what the MFMA uses)
    float rsv[4], biasv[4];
    {
        float rs = 0.f;
        #pragma unroll
        for (int s = 0; s < 16; ++s)
            #pragma unroll
            for (int i = 0; i < 8; ++i) rs += (float)wihF[s][i];
        rs += __shfl_xor(rs, 16);
        rs += __shfl_xor(rs, 32);      // lane l16 holds rowsum of wave row l16
        #pragma unroll
        for (int g = 0; g < 4; ++g) {
            rsv[g]   = __shfl(rs, g * 4 + quad);   // row j = g*HH + kc
            const int j = g * HH + kc;
            biasv[g] = bih[j] + bhh[j];
        }
    }

    // ---- h slot addressing (B-fragment layout position for (m=kc, n=bc)) ----
    // u16 idx = ((((buf*2+dir)*2+ni)*16 + s)*64 + lane)*8 + i ; per buf: 16384 u32
    const int sw = kc >> 5, qw = (kc >> 3) & 3, iw = kc & 7;
    const int lanew = qw * 16 + l16;
    unsigned* hfrag32 = (unsigned*)hfrag;
    const int ws32_rel = (((((dir) * 2 + ni) * 16 + sw) * 64 + lanew) * 8 + iw) >> 1;
    const u64* h64 = (const u64*)hfrag;

    // ---- init: buf0 = h_init(0), bufs 1-3 = sentinel; xring = sentinel ----
    if (!(quad & 1)) {
        AT_STORE(&hfrag32[0 * 16384 + ws32_rel], 0u);
        AT_STORE(&hfrag32[1 * 16384 + ws32_rel], CLR32);
        AT_STORE(&hfrag32[2 * 16384 + ws32_rel], CLR32);
        AT_STORE(&hfrag32[3 * 16384 + ws32_rel], CLR32);
    }
    if (dir == 1 && kc == (HH - 1)) {
        #pragma unroll
        for (int b2 = 0; b2 < 4; ++b2) AT_STORE(&xring[b2 * BB + bc], CLRF);
    }

    __shared__ __align__(16) float gbuf[8][16][20];  // wave-private gate transpose

    arrive_flag(iflags, bid);
    f32x4 un0 = (f32x4){0.f, 0.f, 0.f, 0.f};
    f32x4 un1 = (f32x4){0.f, 0.f, 0.f, 0.f};
    UGEMM_HALF(0, 0);                 // t=0 input GEMM hides in the init barrier
    UGEMM_HALF(0, 8);
    wait_flag(iflags);

    f32x4 gih = un0 + un1;
    float c = 0.f;

    for (int t = 0; t < TT; ++t) {
        #pragma unroll 1
        for (int pass = 0; pass < 2; ++pass) {
            const int n    = t * 2 + pass;
            const int rbuf = n & 3;            // read: data written for pass n
            const int wbuf = (n + 1) & 3;      // write: data for pass n+1
            const int cbuf = (n + 3) & 3;      // clear: buffer consumed at pass n-1

            // ---- poll-on-data: the poll load IS the data load ----
            // Validity by content (sentinel), no flags. Completing this poll
            // certifies every block finished its pass n-1 reads (its pass-n
            // data store data-depends on them) -> clearing cbuf below is safe.
            u64 ha[16], hb[16];
            unsigned rdys = 0;
            bool xok = (pass == 0);
            unsigned xbits = 0;
            const int rb = ((rbuf * 2 + dir) * 2 + ni) * 2048 + lane * 2;
            for (;;) {
                #pragma unroll
                for (int s = 0; s < 16; ++s) if (!((rdys >> s) & 1)) {
                    ha[s] = AT_LOAD(&h64[rb + s * 128]);
                    hb[s] = AT_LOAD(&h64[rb + s * 128 + 1]);
                }
                if (!xok) xbits = AT_LOAD(&xring[rbuf * BB + bc]);
                bool allr = true;
                #pragma unroll
                for (int s = 0; s < 16; ++s) if (!((rdys >> s) & 1)) {
                    bool ok = ((unsigned)ha[s] != CLR32) && ((unsigned)(ha[s] >> 32) != CLR32)
                           && ((unsigned)hb[s] != CLR32) && ((unsigned)(hb[s] >> 32) != CLR32);
                    if (__all(ok)) rdys |= (1u << s); else allr = false;
                }
                if (!xok) { if (__all(xbits != CLRF)) xok = true; else allr = false; }
                if (allr && xok) break;
            }
            const float xc = pass ? __builtin_bit_cast(float, xbits) : 0.f;

            // ---- recurrent GEMM ----
            f32x4 acc0 = gih;
            f32x4 acc1 = (f32x4){0.f, 0.f, 0.f, 0.f};
            #pragma unroll
            for (int s = 0; s < 16; ++s) {
                union { u64 q[2]; bf16x8 v; } cvt;
                cvt.q[0] = ha[s]; cvt.q[1] = hb[s];
                if (s & 1) acc1 = __builtin_amdgcn_mfma_f32_16x16x32_bf16(whhF[s], cvt.v, acc1, 0, 0, 0);
                else       acc0 = __builtin_amdgcn_mfma_f32_16x16x32_bf16(whhF[s], cvt.v, acc0, 0, 0, 0);
            }
            f32x4 acc = acc0 + acc1;

            // ---- D-layout -> per-cell gates via wave-private LDS ----
            float4 gw; gw.x = acc[0]; gw.y = acc[1]; gw.z = acc[2]; gw.w = acc[3];
            *(float4*)&gbuf[wid][l16][quad * 4] = gw;
            __syncthreads();
            float gI = gbuf[wid][l16][ 0 + quad] + biasv[0] + xc * rsv[0];
            float gF = gbuf[wid][l16][ 4 + quad] + biasv[1] + xc * rsv[1];
            float gG = gbuf[wid][l16][ 8 + quad] + biasv[2] + xc * rsv[2];
            float gO = gbuf[wid][l16][12 + quad] + biasv[3] + xc * rsv[3];

            float ig = sigm(gI), fg = sigm(gF), gg = tanh_fast(gG), og = sigm(gO);
            c = fg * c + ig * gg;
            float h = og * tanh_fast(c);

            // ---- publish h (fire-and-forget; content self-validates) ----
            float hp = __shfl_xor(h, 16);
            if (dir == 1 && kc == (HH - 1)) {
                xhat[pass * (TT * BB) + t * BB + bc] = h;   // plain store, epilogue only
                AT_STORE(&xring[wbuf * BB + bc], __builtin_bit_cast(unsigned, h));
            }
            if (!(quad & 1)) {
                unsigned lo = (unsigned)__builtin_bit_cast(unsigned short, (__bf16)h);
                unsigned hi = (unsigned)__builtin_bit_cast(unsigned short, (__bf16)hp);
                AT_STORE(&hfrag32[wbuf * 16384 + ws32_rel], lo | (hi << 16));
            }

            // ---- clear the buffer consumed last pass (poll certified it) ----
            if (!(quad & 1)) AT_STORE(&hfrag32[cbuf * 16384 + ws32_rel], CLR32);
            if (dir == 1 && kc == (HH - 1)) AT_STORE(&xring[cbuf * BB + bc], CLRF);
            // Drain: clears (and h) complete before anything stored next pass.
            // Keeps the clear->rewrite ordering certificate chain intact.
            __builtin_amdgcn_s_waitcnt(0);

            // half of next timestep's input GEMM per pass (overlaps next poll)
            if (t + 1 < TT) {
                if (pass == 0) {
                    un0 = (f32x4){0.f, 0.f, 0.f, 0.f};
                    un1 = (f32x4){0.f, 0.f, 0.f, 0.f};
                    UGEMM_HALF(t + 1, 0);
                } else {
                    UGEMM_HALF(t + 1, 8);
                }
            }
        }
        gih = un0 + un1;
    }
}

__global__ void epilogue(const float* __restrict__ u, const float* __restrict__ xhat,
                         float* __restrict__ out)
{
    const int i = blockIdx.x * blockDim.x + threadIdx.x;   // over float4 groups
    const float4 uv = ((const float4*)u)[i];
    const int bt = i >> 7;             // 128 float4 per (b,t)
    const int t = bt & (TT - 1);
    const int b = bt >> 10;
    const float s = 0.5f * (xhat[t * BB + b] + xhat[TT * BB + t * BB + b]);
    float4 o;
    o.x = 1.5f * uv.x + s;
    o.y = 1.5f * uv.y + s;
    o.z = 1.5f * uv.z + s;
    o.w = 1.5f * uv.w + s;
    ((float4*)out)[i] = o;
}

extern "C" void kernel_launch(void* const* d_in, const int* in_sizes, int n_in,
                              void* d_out, int out_size, void* d_ws, size_t ws_size,
                              hipStream_t stream) {
    const float* u     = (const float*)d_in[0];
    const float* wih_f = (const float*)d_in[1];
    const float* whh_f = (const float*)d_in[2];
    const float* bih_f = (const float*)d_in[3];
    const float* bhh_f = (const float*)d_in[4];
    const float* wih_b = (const float*)d_in[5];
    const float* whh_b = (const float*)d_in[6];
    const float* bih_b = (const float*)d_in[7];
    const float* bhh_b = (const float*)d_in[8];

    char* ws = (char*)d_ws;
    unsigned short* hfrag = (unsigned short*)(ws + HFRAG_OFF);
    float* xhat           = (float*)(ws + XHAT_OFF);
    unsigned* xring       = (unsigned*)(ws + XRING_OFF);
    int* iflags           = (int*)(ws + IFLAG_OFF);

    lstm_persistent<<<NBLK, NTHR, 0, stream>>>(
        u, wih_f, whh_f, bih_f, bhh_f, wih_b, whh_b, bih_b, bhh_b,
        hfrag, xhat, xring, iflags);

    const int n4 = BB * TT * DD / 4;
    epilogue<<<n4 / 256, 256, 0, stream>>>(u, xhat, (float*)d_out);
}